// Round 1
// baseline (94.486 us; speedup 1.0000x reference)
//
#include <hip/hip_runtime.h>

#define D_DIM 262144
#define T_DIM 24
#define S_DIM 12

static constexpr float EPSF = 1e-6f;

// ---------------- threefry2x32, key = (0,0), 20 rounds ----------------
__device__ __forceinline__ void tf_round(unsigned& x0, unsigned& x1, int r) {
  x0 += x1;
  x1 = (x1 << r) | (x1 >> (32 - r));
  x1 ^= x0;
}

__device__ __forceinline__ void threefry00(unsigned c0, unsigned c1,
                                           unsigned& o0, unsigned& o1) {
  const unsigned ks0 = 0u, ks1 = 0u, ks2 = 0x1BD11BDAu;
  unsigned x0 = c0 + ks0, x1 = c1 + ks1;
  tf_round(x0, x1, 13); tf_round(x0, x1, 15); tf_round(x0, x1, 26); tf_round(x0, x1, 6);
  x0 += ks1; x1 += ks2 + 1u;
  tf_round(x0, x1, 17); tf_round(x0, x1, 29); tf_round(x0, x1, 16); tf_round(x0, x1, 24);
  x0 += ks2; x1 += ks0 + 2u;
  tf_round(x0, x1, 13); tf_round(x0, x1, 15); tf_round(x0, x1, 26); tf_round(x0, x1, 6);
  x0 += ks0; x1 += ks1 + 3u;
  tf_round(x0, x1, 17); tf_round(x0, x1, 29); tf_round(x0, x1, 16); tf_round(x0, x1, 24);
  x0 += ks1; x1 += ks2 + 4u;
  tf_round(x0, x1, 13); tf_round(x0, x1, 15); tf_round(x0, x1, 26); tf_round(x0, x1, 6);
  x0 += ks2; x1 += ks0 + 5u;
  o0 = x0; o1 = x1;
}

// bits -> uniform in [-0.99999994, 1) -> sqrt(2)*erfinv(u)  (XLA f32 path)
__device__ __forceinline__ float bits_to_normal(unsigned bits) {
  const float lo = -0.99999994f;
  const float hi = 1.0f;
  unsigned fb = (bits >> 9) | 0x3f800000u;
  float f = __uint_as_float(fb) - 1.0f;      // [0,1)
  float u = f * (hi - lo) + lo;
  u = fmaxf(lo, u);
  // erfinv, Giles / XLA ErfInv32
  float w = -log1pf(-u * u);
  float p;
  if (w < 5.0f) {
    w = w - 2.5f;
    p = 2.81022636e-08f;
    p = fmaf(p, w, 3.43273939e-07f);
    p = fmaf(p, w, -3.5233877e-06f);
    p = fmaf(p, w, -4.39150654e-06f);
    p = fmaf(p, w, 0.00021858087f);
    p = fmaf(p, w, -0.00125372503f);
    p = fmaf(p, w, -0.00417768164f);
    p = fmaf(p, w, 0.246640727f);
    p = fmaf(p, w, 1.50140941f);
  } else {
    w = sqrtf(w) - 3.0f;
    p = -0.000200214257f;
    p = fmaf(p, w, 0.000100950558f);
    p = fmaf(p, w, 0.00134934322f);
    p = fmaf(p, w, -0.00367342844f);
    p = fmaf(p, w, 0.00573950773f);
    p = fmaf(p, w, -0.0076224613f);
    p = fmaf(p, w, 0.00943887047f);
    p = fmaf(p, w, 1.00167406f);
    p = fmaf(p, w, 2.83297682f);
  }
  return 1.41421356237309515f * (p * u);
}

__global__ __launch_bounds__(256) void pgm_lds_kernel(
    const float* __restrict__ recog_J, const float* __restrict__ recog_h,
    const float* __restrict__ loc_p, const float* __restrict__ Tau_p,
    const float* __restrict__ Lambda_p, const float* __restrict__ A_p,
    const float* __restrict__ b_p,
    float* __restrict__ z_out, float* __restrict__ kl_out,
    float* __restrict__ Ex_out, float* __restrict__ Exx_out) {
  const int d = blockIdx.x * blockDim.x + threadIdx.x;   // grid sized exactly D

  // ---- static per-dim params ----
  float lam[S_DIM], Aa[S_DIM], hb[S_DIM];
  float plogz = 0.0f;   // 0.5*(sum_t lam b^2 - log lam) + 0.5*(tau loc^2 - log tau)
#pragma unroll
  for (int s = 0; s < S_DIM; ++s) {
    float L = Lambda_p[s * D_DIM + d];
    float a = A_p[s * D_DIM + d];
    float bb = b_p[s * D_DIM + d];
    float l = L * L + EPSF;
    lam[s] = l;
    Aa[s] = a;
    hb[s] = l * bb;
    float wgt = (s < 11) ? 2.0f : 1.0f;   // _tile: s=0..10 appear twice, s=11 once
    plogz += wgt * (hb[s] * bb - logf(l));
  }
  float tau, tau_mu;
  {
    float Tv = Tau_p[d];
    float lv = loc_p[d];
    tau = Tv * Tv + EPSF;
    tau_mu = tau * lv;
    plogz += tau * lv * lv - logf(tau);
  }
  plogz *= 0.5f;

  // ---- load recognition potentials (kept for KL stats) ----
  float rJ[T_DIM], rh[T_DIM];
#pragma unroll
  for (int t = 0; t < T_DIM; ++t) {
    rJ[t] = recog_J[t * D_DIM + d];
    rh[t] = recog_h[t * D_DIM + d];
  }

  // ---- forward information filter ----
  float fJ[T_DIM], fh[T_DIM];
  float qlogz = 0.0f;   // q_logZ with the 0.5*LOG_2PI*(T) constant dropped (cancels vs p)
  fJ[0] = tau + rJ[0];
  fh[0] = tau_mu + rh[0];
#pragma unroll
  for (int t = 0; t < T_DIM - 1; ++t) {
    const int s = (t < 12) ? t : t - 12;
    float l = lam[s], a = Aa[s];
    float jab = a * l;
    float jaa = a * jab;
    float ha = -a * hb[s];
    float denom = fJ[t] + jaa;
    float inv = 1.0f / denom;
    float hc = fh[t] + ha;
    qlogz += -0.5f * logf(denom) + 0.5f * hc * hc * inv;
    fJ[t + 1] = l - jab * jab * inv + rJ[t + 1];
    fh[t + 1] = hb[s] + jab * hc * inv + rh[t + 1];
  }
  const float fJT = fJ[T_DIM - 1];
  const float fhT = fh[T_DIM - 1];
  qlogz += -0.5f * logf(fJT) + 0.5f * fhT * fhT / fJT;

  // ---- t = 23 (last step) ----
  float eps_st[S_DIM];   // stash eps[0..11], produced while consuming eps[12..23]
  float ExT = fhT / fJT;
  float VarT = 1.0f / fJT;
  float eps23;
  {
    unsigned o0, o1;
    threefry00((unsigned)(11 * D_DIM + d), (unsigned)(23 * D_DIM + d), o0, o1);
    eps_st[11] = bits_to_normal(o0);
    eps23 = bits_to_normal(o1);
  }
  float zT = ExT + eps23 * rsqrtf(fJT);
  float ExxT = VarT + ExT * ExT;
  float kld = -0.5f * rJ[T_DIM - 1] * ExxT + rh[T_DIM - 1] * ExT;
  z_out[(T_DIM - 1) * D_DIM + d] = zT;
  Ex_out[(T_DIM - 1) * D_DIM + d] = ExT;
  Exx_out[(T_DIM - 1) * D_DIM + d] = ExxT;

  // ---- fused backward: RTS smoother + posterior sample + KL stats ----
  float Exn = ExT, Varn = VarT, zn = zT;
#pragma unroll
  for (int t = T_DIM - 2; t >= 0; --t) {
    const int s = (t < 12) ? t : t - 12;
    float l = lam[s], a = Aa[s];
    float jab = a * l;
    float jaa = a * jab;
    float ha = -a * hb[s];
    float denom = fJ[t] + jaa;
    float inv = 1.0f / denom;
    float hc = fh[t] + ha;

    float e;
    if (t >= 12) {
      unsigned o0, o1;
      threefry00((unsigned)((t - 12) * D_DIM + d), (unsigned)(t * D_DIM + d), o0, o1);
      eps_st[t - 12] = bits_to_normal(o0);
      e = bits_to_normal(o1);
    } else {
      e = eps_st[t];
    }

    float g = jab * inv;
    float Ex = (hc + jab * Exn) * inv;
    float Var = inv + g * g * Varn;
    float zt = (hc + jab * zn) * inv + e * rsqrtf(denom);
    float Exx = Var + Ex * Ex;
    kld += -0.5f * rJ[t] * Exx + rh[t] * Ex;

    z_out[t * D_DIM + d] = zt;
    Ex_out[t * D_DIM + d] = Ex;
    Exx_out[t * D_DIM + d] = Exx;

    Exn = Ex; Varn = Var; zn = zt;
  }

  kld += plogz - qlogz;

  // ---- KL reduction: wave-reduce then one atomic per wave ----
#pragma unroll
  for (int off = 32; off > 0; off >>= 1)
    kld += __shfl_down(kld, off, 64);
  if ((threadIdx.x & 63) == 0)
    atomicAdd(kl_out, kld);
}

extern "C" void kernel_launch(void* const* d_in, const int* in_sizes, int n_in,
                              void* d_out, int out_size, void* d_ws, size_t ws_size,
                              hipStream_t stream) {
  const float* recog_J = (const float*)d_in[0];
  const float* recog_h = (const float*)d_in[1];
  const float* loc_p   = (const float*)d_in[2];
  const float* Tau_p   = (const float*)d_in[3];
  const float* Lambda_p = (const float*)d_in[4];
  const float* A_p     = (const float*)d_in[5];
  const float* b_p     = (const float*)d_in[6];

  float* out = (float*)d_out;
  float* z_out  = out;                                    // T*D
  float* kl_out = out + (size_t)T_DIM * D_DIM;            // 1
  float* Ex_out = kl_out + 1;                             // T*D
  float* Exx_out = Ex_out + (size_t)T_DIM * D_DIM;        // T*D

  hipMemsetAsync(kl_out, 0, sizeof(float), stream);

  dim3 block(256);
  dim3 grid(D_DIM / 256);
  pgm_lds_kernel<<<grid, block, 0, stream>>>(recog_J, recog_h, loc_p, Tau_p,
                                             Lambda_p, A_p, b_p,
                                             z_out, kl_out, Ex_out, Exx_out);
}